// Round 5
// baseline (227.696 us; speedup 1.0000x reference)
//
#include <hip/hip_runtime.h>
#include <hip/hip_bf16.h>

#define D_ 256
#define NROWS_Z 512
#define NROWS 528
#define KQ 131072
#define NBLK 256          // queue chunks
#define NBLK_BIG 512      // 2 row-groups x 256 chunks
#define KC 512
#define SUBT 32
// 1/tau * log2(e): logits computed directly in log2 domain
#define SCALE_A (14.285714285714286f * 1.4426950408889634f)
#define LN2 0.6931471805599453f

typedef __attribute__((ext_vector_type(8))) short short8;
typedef __attribute__((ext_vector_type(4))) float f32x4;

__device__ __forceinline__ float exp2fast(float x) {
  float r; asm("v_exp_f32 %0, %1" : "=v"(r) : "v"(x)); return r;
}
__device__ __forceinline__ float log2fast(float x) {
  float r; asm("v_log_f32 %0, %1" : "=v"(r) : "v"(x)); return r;
}

__device__ __forceinline__ short bf16r(float x) {
  union { float f; unsigned u; } c; c.f = x;
  unsigned r = (c.u + 0x7fffu + ((c.u >> 16) & 1u)) >> 16;  // RNE
  return (short)r;
}

// merge two (max, sum2^) lse states, log2 domain
__device__ __forceinline__ void merge_ms(float& m, float& s, float m2, float s2) {
  float mm = fmaxf(m, m2);
  s = s * exp2fast(m - mm) + s2 * exp2fast(m2 - mm);
  m = mm;
}

// T13 defer-max online update: wave-uniform rescale branch, 1 trans common path
__device__ __forceinline__ void upd(float& m, float& s, float v) {
  float d = v - m;
  if (__builtin_expect(__any(d > 8.f), 0)) {
    const float mn = fmaxf(m, v);
    s *= exp2fast(m - mn);
    m = mn; d = v - m;
  }
  s += exp2fast(d);
}

// 8 x f32 -> 8 x bf16 via packed cvt (RNE)
__device__ __forceinline__ short8 cvt8(float4 a, float4 b) {
  union { unsigned u[4]; short8 s; } o;
  asm("v_cvt_pk_bf16_f32 %0, %1, %2" : "=v"(o.u[0]) : "v"(a.x), "v"(a.y));
  asm("v_cvt_pk_bf16_f32 %0, %1, %2" : "=v"(o.u[1]) : "v"(a.z), "v"(a.w));
  asm("v_cvt_pk_bf16_f32 %0, %1, %2" : "=v"(o.u[2]) : "v"(b.x), "v"(b.y));
  asm("v_cvt_pk_bf16_f32 %0, %1, %2" : "=v"(o.u[3]) : "v"(b.z), "v"(b.w));
  return o.s;
}

// ---------------- prep: Abf[528][256] scaled (log2 domain), Zp[512][256] plain,
// ---------------- and per-row smoothness partials ----------------
__global__ void prep_kernel(const float* __restrict__ z, const float* __restrict__ g,
                            short* __restrict__ Abf, short* __restrict__ Zp,
                            float* __restrict__ smoothp) {
  const int r = blockIdx.x, d = threadIdx.x;
  const float v = (r < NROWS_Z) ? z[r * D_ + d] : g[(r - NROWS_Z) * D_ + d];
  Abf[r * D_ + d] = bf16r(v * SCALE_A);
  if (r < NROWS_Z) {
    Zp[r * D_ + d] = bf16r(v);
    float acc = 0.f;
    if ((r & 31) != 31) { const float dv = z[(r + 1) * D_ + d] - v; acc = dv * dv; }
#pragma unroll
    for (int mask = 1; mask < 64; mask <<= 1) acc += __shfl_xor(acc, mask);
    __shared__ float red[4];
    if ((d & 63) == 0) red[d >> 6] = acc;
    __syncthreads();
    if (d == 0) smoothp[r] = red[0] + red[1] + red[2] + red[3];
  }
}

// ---------------- big: per-row online lse over 131072 queue columns ----------------
// 512 blocks = 2 row-groups x 256 queue chunks; 8 waves x 32 rows register-resident
// (afrag = 64 VGPR, fits the compiler's 128-reg budget). Depth-2 double buffer.
// Blocks j and j+256 share queue chunk j and land on the same XCD (j mod 8).
__global__ __launch_bounds__(512, 4) void big_kernel(
    const float* __restrict__ queue, const short* __restrict__ Abf,
    float2* __restrict__ zpart, float2* __restrict__ gpart) {
  const int tid = threadIdx.x;
  const int chunk = blockIdx.x & 255;
  const int rowgroup = blockIdx.x >> 8;     // 0: rows 0..255 (+g), 1: rows 256..511
  const int wid = tid >> 6, lane = tid & 63;
  const int l15 = lane & 15, l4 = lane >> 4;

  __shared__ __align__(16) char qs[2][16 * 512];  // 2 x (16 rows x 256 bf16), swizzled
  __shared__ float2 gbuf[8 * 16];

  // A fragments resident: 2 slabs x 8 ksteps x 16B = 64 VGPR
  short8 afrag[2][8];
#pragma unroll
  for (int s = 0; s < 2; ++s) {
    const short* base = Abf + (rowgroup * 256 + wid * 32 + s * 16 + l15) * D_ + l4 * 8;
#pragma unroll
    for (int k = 0; k < 8; ++k) afrag[s][k] = *(const short8*)(base + k * 32);
  }
  const short* gbase = Abf + (NROWS_Z + l15) * D_ + l4 * 8;

  float mz[2][4], sz[2][4];
#pragma unroll
  for (int s = 0; s < 2; ++s)
#pragma unroll
    for (int r = 0; r < 4; ++r) { mz[s][r] = -1e30f; sz[s][r] = 0.f; }
  float mg[4], sg[4];
#pragma unroll
  for (int r = 0; r < 4; ++r) { mg[r] = -1e30f; sg[r] = 0.f; }

  const int srow = tid >> 5;       // 16 staging rows, 32 threads each
  const int sslot = tid & 31;      // 16B slot within row
  const int woff = srow * 512 + (((sslot ^ srow) & 31) << 4);
  const float* qbase = queue + (size_t)(chunk * KC + srow) * D_ + sslot * 8;

  const f32x4 fz = {0.f, 0.f, 0.f, 0.f};
  const bool dog = (rowgroup == 0);

  // prologue: stage tile 0, preload tile 1 into regs
  float4 fa0 = *(const float4*)qbase;
  float4 fa1 = *(const float4*)(qbase + 4);
  float4 fb0 = *(const float4*)(qbase + 16 * D_);
  float4 fb1 = *(const float4*)(qbase + 16 * D_ + 4);
  *(short8*)(qs[0] + woff) = cvt8(fa0, fa1);
  __syncthreads();

  // compute tile in BUF; g-MFMA fused (shares the bf ds_read) on its wave's turn
#define COMPUTE(BUF, ST)                                                              \
  {                                                                                   \
    const char* qb = qs[BUF];                                                         \
    f32x4 acc0 = fz, acc1 = fz;                                                       \
    if (dog && ((ST) & 7) == wid) {                                                   \
      f32x4 accg = fz;                                                                \
      _Pragma("unroll")                                                               \
      for (int k = 0; k < 8; ++k) {                                                   \
        const short8 bf = *(const short8*)(qb + l15 * 512 + ((((k * 4 + l4) ^ l15) & 31) << 4)); \
        acc0 = __builtin_amdgcn_mfma_f32_16x16x32_bf16(afrag[0][k], bf, acc0, 0, 0, 0); \
        acc1 = __builtin_amdgcn_mfma_f32_16x16x32_bf16(afrag[1][k], bf, acc1, 0, 0, 0); \
        const short8 ag = *(const short8*)(gbase + k * 32);                           \
        accg = __builtin_amdgcn_mfma_f32_16x16x32_bf16(ag, bf, accg, 0, 0, 0);        \
      }                                                                               \
      _Pragma("unroll")                                                               \
      for (int r = 0; r < 4; ++r) upd(mg[r], sg[r], accg[r]);                         \
    } else {                                                                          \
      _Pragma("unroll")                                                               \
      for (int k = 0; k < 8; ++k) {                                                   \
        const short8 bf = *(const short8*)(qb + l15 * 512 + ((((k * 4 + l4) ^ l15) & 31) << 4)); \
        acc0 = __builtin_amdgcn_mfma_f32_16x16x32_bf16(afrag[0][k], bf, acc0, 0, 0, 0); \
        acc1 = __builtin_amdgcn_mfma_f32_16x16x32_bf16(afrag[1][k], bf, acc1, 0, 0, 0); \
      }                                                                               \
    }                                                                                 \
    _Pragma("unroll")                                                                 \
    for (int r = 0; r < 4; ++r) upd(mz[0][r], sz[0][r], acc0[r]);                     \
    _Pragma("unroll")                                                                 \
    for (int r = 0; r < 4; ++r) upd(mz[1][r], sz[1][r], acc1[r]);                     \
  }

  for (int st = 0; st < SUBT; st += 2) {
    // ---- body A: load tile st+2; write tile st+1 (buf1); compute tile st (buf0)
    if (st + 2 < SUBT) {
      const float* qp = qbase + (st + 2) * (16 * D_);
      fa0 = *(const float4*)qp;
      fa1 = *(const float4*)(qp + 4);
    }
    *(short8*)(qs[1] + woff) = cvt8(fb0, fb1);
    COMPUTE(0, st)
    __syncthreads();

    // ---- body B: load tile st+3; write tile st+2 (buf0); compute tile st+1 (buf1)
    if (st + 3 < SUBT) {
      const float* qp = qbase + (st + 3) * (16 * D_);
      fb0 = *(const float4*)qp;
      fb1 = *(const float4*)(qp + 4);
    }
    if (st + 2 < SUBT) *(short8*)(qs[0] + woff) = cvt8(fa0, fa1);
    COMPUTE(1, st + 1)
    __syncthreads();
  }

  // merge across the 16 column-lanes
#pragma unroll
  for (int s = 0; s < 2; ++s)
#pragma unroll
    for (int r = 0; r < 4; ++r) {
#pragma unroll
      for (int mask = 1; mask < 16; mask <<= 1) {
        const float om = __shfl_xor(mz[s][r], mask);
        const float os = __shfl_xor(sz[s][r], mask);
        merge_ms(mz[s][r], sz[s][r], om, os);
      }
    }

  if (l15 == 0) {
#pragma unroll
    for (int s = 0; s < 2; ++s)
#pragma unroll
      for (int r = 0; r < 4; ++r) {
        const int row = rowgroup * 256 + wid * 32 + s * 16 + l4 * 4 + r;
        zpart[row * NBLK + chunk] = make_float2(mz[s][r], sz[s][r]);
      }
  }

  if (dog) {
#pragma unroll
    for (int r = 0; r < 4; ++r) {
#pragma unroll
      for (int mask = 1; mask < 16; mask <<= 1) {
        const float om = __shfl_xor(mg[r], mask);
        const float os = __shfl_xor(sg[r], mask);
        merge_ms(mg[r], sg[r], om, os);
      }
    }
    if (l15 == 0) {
#pragma unroll
      for (int r = 0; r < 4; ++r)
        gbuf[wid * 16 + l4 * 4 + r] = make_float2(mg[r], sg[r]);
    }
    __syncthreads();
    if (tid < 16) {
      float m = gbuf[tid].x, s = gbuf[tid].y;
      for (int w = 1; w < 8; ++w) merge_ms(m, s, gbuf[w * 16 + tid].x, gbuf[w * 16 + tid].y);
      gpart[tid * NBLK + chunk] = make_float2(m, s);
    }
  }
}

// ---------------- zmm: masked lse over the 512 z columns via MFMA + pos extraction ----
__global__ __launch_bounds__(512) void zmm_kernel(
    const short* __restrict__ Abf, const short* __restrict__ Zp,
    float2* __restrict__ zcol, float* __restrict__ posll, float* __restrict__ posgl) {
  const int tid = threadIdx.x;
  const int wid = tid >> 6, lane = tid & 63;
  const int l15 = lane & 15, l4 = lane >> 4;
  const int r0 = blockIdx.x * 16;

  short8 af[8];
#pragma unroll
  for (int k = 0; k < 8; ++k)
    af[k] = *(const short8*)(Abf + (r0 + l15) * D_ + l4 * 8 + k * 32);

  float m[4], s[4];
#pragma unroll
  for (int r = 0; r < 4; ++r) { m[r] = -1e30f; s[r] = 0.f; }

  for (int st = 0; st < 4; ++st) {
    const int c0 = wid * 64 + st * 16;
    const f32x4 fz = {0.f, 0.f, 0.f, 0.f};
    f32x4 acc = fz;
#pragma unroll
    for (int k = 0; k < 8; ++k) {
      const short8 bq = *(const short8*)(Zp + (c0 + l15) * D_ + l4 * 8 + k * 32);
      acc = __builtin_amdgcn_mfma_f32_16x16x32_bf16(af[k], bq, acc, 0, 0, 0);
    }
#pragma unroll
    for (int r = 0; r < 4; ++r) {
      const int row = r0 + l4 * 4 + r;
      const int col = c0 + l15;
      const float v = acc[r];
      bool masked;
      if (r0 < NROWS_Z) {
        if (col == row + 1) posll[row] = v * LN2;
        masked = (col == row) || (col == row + 1);
      } else {
        const int b = row - NROWS_Z;
        const bool own = ((col >> 5) == b);
        if (own) posgl[col] = v * LN2;
        masked = own;
      }
      if (!masked) upd(m[r], s[r], v);
    }
  }
#pragma unroll
  for (int r = 0; r < 4; ++r) {
#pragma unroll
    for (int mask = 1; mask < 16; mask <<= 1) {
      const float om = __shfl_xor(m[r], mask);
      const float os = __shfl_xor(s[r], mask);
      merge_ms(m[r], s[r], om, os);
    }
  }
  __shared__ float2 lds[8][16];
  if (l15 == 0) {
#pragma unroll
    for (int r = 0; r < 4; ++r) lds[wid][l4 * 4 + r] = make_float2(m[r], s[r]);
  }
  __syncthreads();
  if (tid < 16) {
    float mm = lds[0][tid].x, ss = lds[0][tid].y;
    for (int w = 1; w < 8; ++w) merge_ms(mm, ss, lds[w][tid].x, lds[w][tid].y);
    zcol[r0 + tid] = make_float2(mm, ss);
  }
}

// ---------------- reduce: merge 256 chunk partials + zcol partial per row ----------------
__global__ void reduce_kernel(const float2* __restrict__ zpart, const float2* __restrict__ gpart,
                              const float2* __restrict__ zcol, float* __restrict__ lse_row) {
  const int r = blockIdx.x, tid = threadIdx.x;
  const float2 p = (r < NROWS_Z) ? zpart[r * NBLK + tid] : gpart[(r - NROWS_Z) * NBLK + tid];
  float m = p.x, s = p.y;
  __shared__ float2 red[4];
#pragma unroll
  for (int mask = 1; mask < 64; mask <<= 1) {
    const float om = __shfl_xor(m, mask);
    const float os = __shfl_xor(s, mask);
    merge_ms(m, s, om, os);
  }
  if ((tid & 63) == 0) red[tid >> 6] = make_float2(m, s);
  __syncthreads();
  if (tid == 0) {
    for (int w = 1; w < 4; ++w) merge_ms(m, s, red[w].x, red[w].y);
    const float2 zc = zcol[r];
    merge_ms(m, s, zc.x, zc.y);
    lse_row[r] = LN2 * (m + log2fast(s));   // back to natural log
  }
}

// ---------------- final: losses ----------------
__global__ void final_kernel(const float* __restrict__ lse_row, const float* __restrict__ posll,
                             const float* __restrict__ posgl, const float* __restrict__ smoothp,
                             float* __restrict__ out) {
  const int tid = threadIdx.x;
  float a_ll = 0.f, a_gl = 0.f, a_sm = 0.f;
  for (int i = tid; i < 496; i += 256) {
    const int b = i / 31, t = i - b * 31;
    const int a = b * 32 + t;
    const float pos = posll[a], lse = lse_row[a];
    const float d = lse - pos;
    a_ll += (d > 0.f) ? d + log1pf(__expf(-d)) : log1pf(__expf(d));
  }
  for (int i = tid; i < 512; i += 256) {
    const float pos = posgl[i], lse = lse_row[NROWS_Z + (i >> 5)];
    const float d = lse - pos;
    a_gl += (d > 0.f) ? d + log1pf(__expf(-d)) : log1pf(__expf(d));
  }
  for (int i = tid; i < 512; i += 256) a_sm += smoothp[i];

  __shared__ float red[4];
  float sums[3] = {a_ll, a_gl, a_sm};
  float tot[3];
  for (int j = 0; j < 3; ++j) {
    float v = sums[j];
#pragma unroll
    for (int mask = 1; mask < 64; mask <<= 1) v += __shfl_xor(v, mask);
    __syncthreads();
    if ((tid & 63) == 0) red[tid >> 6] = v;
    __syncthreads();
    tot[j] = red[0] + red[1] + red[2] + red[3];
  }
  if (tid == 0)
    out[0] = tot[0] / 496.f + 0.5f * (tot[1] / 512.f) + 0.1f * (tot[2] / 496.f);
}

extern "C" void kernel_launch(void* const* d_in, const int* in_sizes, int n_in,
                              void* d_out, int out_size, void* d_ws, size_t ws_size,
                              hipStream_t stream) {
  const float* z = (const float*)d_in[0];      // [512,256]
  const float* g = (const float*)d_in[1];      // [16,256]
  const float* queue = (const float*)d_in[3];  // [131072,256]
  float* out = (float*)d_out;
  char* ws = (char*)d_ws;

  constexpr size_t OFF_A = 0;                         // 528*256*2 = 270336
  constexpr size_t OFF_ZP = OFF_A + 270336;           // 512*256*2 = 262144
  constexpr size_t OFF_ZPART = OFF_ZP + 262144;       // 512*256*8 = 1048576
  constexpr size_t OFF_GPART = OFF_ZPART + 1048576;   // 16*256*8  = 32768
  constexpr size_t OFF_ZCOL = OFF_GPART + 32768;      // 528*8     = 4224
  constexpr size_t OFF_POSLL = OFF_ZCOL + 4224;       // 512*4
  constexpr size_t OFF_POSGL = OFF_POSLL + 2048;      // 512*4
  constexpr size_t OFF_SM = OFF_POSGL + 2048;         // 512*4
  constexpr size_t OFF_LSE = OFF_SM + 2048;           // 528*4

  short* Abf = (short*)(ws + OFF_A);
  short* Zp = (short*)(ws + OFF_ZP);
  float2* zpart = (float2*)(ws + OFF_ZPART);
  float2* gpart = (float2*)(ws + OFF_GPART);
  float2* zcol = (float2*)(ws + OFF_ZCOL);
  float* posll = (float*)(ws + OFF_POSLL);
  float* posgl = (float*)(ws + OFF_POSGL);
  float* smoothp = (float*)(ws + OFF_SM);
  float* lse_row = (float*)(ws + OFF_LSE);

  prep_kernel<<<NROWS, 256, 0, stream>>>(z, g, Abf, Zp, smoothp);
  big_kernel<<<NBLK_BIG, 512, 0, stream>>>(queue, Abf, zpart, gpart);
  zmm_kernel<<<33, 512, 0, stream>>>(Abf, Zp, zcol, posll, posgl);
  reduce_kernel<<<NROWS, 256, 0, stream>>>(zpart, gpart, zcol, lse_row);
  final_kernel<<<1, 256, 0, stream>>>(lse_row, posll, posgl, smoothp, out);
}

// Round 6
// 122.642 us; speedup vs baseline: 1.8566x; 1.8566x over previous
//
#include <hip/hip_runtime.h>
#include <hip/hip_bf16.h>

#define D_ 256
#define NROWS_Z 512
#define NROWS 528
#define KQ 131072
#define NBLK 256          // queue chunks
#define NBLK_BIG 512      // 2 row-groups x 256 chunks
#define KC 512
#define SUBT 32
// 1/tau * log2(e): logits computed directly in log2 domain
#define SCALE_A (14.285714285714286f * 1.4426950408889634f)
#define LN2 0.6931471805599453f

typedef __attribute__((ext_vector_type(8))) short short8;
typedef __attribute__((ext_vector_type(4))) float f32x4;

__device__ __forceinline__ float exp2fast(float x) {
  float r; asm("v_exp_f32 %0, %1" : "=v"(r) : "v"(x)); return r;
}
__device__ __forceinline__ float log2fast(float x) {
  float r; asm("v_log_f32 %0, %1" : "=v"(r) : "v"(x)); return r;
}

__device__ __forceinline__ short bf16r(float x) {
  union { float f; unsigned u; } c; c.f = x;
  unsigned r = (c.u + 0x7fffu + ((c.u >> 16) & 1u)) >> 16;  // RNE
  return (short)r;
}

// merge two (max, sum2^) lse states, log2 domain
__device__ __forceinline__ void merge_ms(float& m, float& s, float m2, float s2) {
  float mm = fmaxf(m, m2);
  s = s * exp2fast(m - mm) + s2 * exp2fast(m2 - mm);
  m = mm;
}

// T13 defer-max online update: wave-uniform rescale branch, 1 trans common path
__device__ __forceinline__ void upd(float& m, float& s, float v) {
  float d = v - m;
  if (__builtin_expect(__any(d > 8.f), 0)) {
    const float mn = fmaxf(m, v);
    s *= exp2fast(m - mn);
    m = mn; d = v - m;
  }
  s += exp2fast(d);
}

// 8 x f32 -> 8 x bf16 via packed cvt (RNE)
__device__ __forceinline__ short8 cvt8(float4 a, float4 b) {
  union { unsigned u[4]; short8 s; } o;
  asm("v_cvt_pk_bf16_f32 %0, %1, %2" : "=v"(o.u[0]) : "v"(a.x), "v"(a.y));
  asm("v_cvt_pk_bf16_f32 %0, %1, %2" : "=v"(o.u[1]) : "v"(a.z), "v"(a.w));
  asm("v_cvt_pk_bf16_f32 %0, %1, %2" : "=v"(o.u[2]) : "v"(b.x), "v"(b.y));
  asm("v_cvt_pk_bf16_f32 %0, %1, %2" : "=v"(o.u[3]) : "v"(b.z), "v"(b.w));
  return o.s;
}

// ---------------- prep: Abf[528][256] scaled (log2 domain), Zp[512][256] plain,
// ---------------- and per-row smoothness partials ----------------
__global__ void prep_kernel(const float* __restrict__ z, const float* __restrict__ g,
                            short* __restrict__ Abf, short* __restrict__ Zp,
                            float* __restrict__ smoothp) {
  const int r = blockIdx.x, d = threadIdx.x;
  const float v = (r < NROWS_Z) ? z[r * D_ + d] : g[(r - NROWS_Z) * D_ + d];
  Abf[r * D_ + d] = bf16r(v * SCALE_A);
  if (r < NROWS_Z) {
    Zp[r * D_ + d] = bf16r(v);
    float acc = 0.f;
    if ((r & 31) != 31) { const float dv = z[(r + 1) * D_ + d] - v; acc = dv * dv; }
#pragma unroll
    for (int mask = 1; mask < 64; mask <<= 1) acc += __shfl_xor(acc, mask);
    __shared__ float red[4];
    if ((d & 63) == 0) red[d >> 6] = acc;
    __syncthreads();
    if (d == 0) smoothp[r] = red[0] + red[1] + red[2] + red[3];
  }
}

// ---------------- big: per-row online lse over 131072 queue columns ----------------
// 512 blocks = 2 row-groups x 256 queue chunks; 8 waves x 32 rows register-resident
// (afrag = 64 VGPR; live set ~110 fits the 128-VGPR bucket that launch_bounds(512,2)
// reliably selects -- R2 evidence). Depth-2 double buffer. 2 blocks/CU.
__global__ __launch_bounds__(512, 2) void big_kernel(
    const float* __restrict__ queue, const short* __restrict__ Abf,
    float2* __restrict__ zpart, float2* __restrict__ gpart) {
  const int tid = threadIdx.x;
  const int chunk = blockIdx.x & 255;
  const int rowgroup = blockIdx.x >> 8;     // 0: rows 0..255 (+g), 1: rows 256..511
  const int wid = tid >> 6, lane = tid & 63;
  const int l15 = lane & 15, l4 = lane >> 4;

  __shared__ __align__(16) char qs[2][16 * 512];  // 2 x (16 rows x 256 bf16), swizzled
  __shared__ float2 gbuf[8 * 16];

  // A fragments resident: 2 slabs x 8 ksteps x 16B = 64 VGPR
  short8 afrag[2][8];
#pragma unroll
  for (int s = 0; s < 2; ++s) {
    const short* base = Abf + (rowgroup * 256 + wid * 32 + s * 16 + l15) * D_ + l4 * 8;
#pragma unroll
    for (int k = 0; k < 8; ++k) afrag[s][k] = *(const short8*)(base + k * 32);
  }
  const short* gbase = Abf + (NROWS_Z + l15) * D_ + l4 * 8;

  float mz[2][4], sz[2][4];
#pragma unroll
  for (int s = 0; s < 2; ++s)
#pragma unroll
    for (int r = 0; r < 4; ++r) { mz[s][r] = -1e30f; sz[s][r] = 0.f; }
  float mg[4], sg[4];
#pragma unroll
  for (int r = 0; r < 4; ++r) { mg[r] = -1e30f; sg[r] = 0.f; }

  const int srow = tid >> 5;       // 16 staging rows, 32 threads each
  const int sslot = tid & 31;      // 16B slot within row
  const int woff = srow * 512 + (((sslot ^ srow) & 31) << 4);
  const float* qbase = queue + (size_t)(chunk * KC + srow) * D_ + sslot * 8;

  const f32x4 fz = {0.f, 0.f, 0.f, 0.f};
  const bool dog = (rowgroup == 0);

  // prologue: stage tile 0, preload tile 1 into regs
  float4 fa0 = *(const float4*)qbase;
  float4 fa1 = *(const float4*)(qbase + 4);
  float4 fb0 = *(const float4*)(qbase + 16 * D_);
  float4 fb1 = *(const float4*)(qbase + 16 * D_ + 4);
  *(short8*)(qs[0] + woff) = cvt8(fa0, fa1);
  __syncthreads();

  // compute tile in BUF; g-MFMA fused (shares the bf ds_read) on its wave's turn
#define COMPUTE(BUF, ST)                                                              \
  {                                                                                   \
    const char* qb = qs[BUF];                                                         \
    f32x4 acc0 = fz, acc1 = fz;                                                       \
    if (dog && ((ST) & 7) == wid) {                                                   \
      f32x4 accg = fz;                                                                \
      _Pragma("unroll")                                                               \
      for (int k = 0; k < 8; ++k) {                                                   \
        const short8 bf = *(const short8*)(qb + l15 * 512 + ((((k * 4 + l4) ^ l15) & 31) << 4)); \
        acc0 = __builtin_amdgcn_mfma_f32_16x16x32_bf16(afrag[0][k], bf, acc0, 0, 0, 0); \
        acc1 = __builtin_amdgcn_mfma_f32_16x16x32_bf16(afrag[1][k], bf, acc1, 0, 0, 0); \
        const short8 ag = *(const short8*)(gbase + k * 32);                           \
        accg = __builtin_amdgcn_mfma_f32_16x16x32_bf16(ag, bf, accg, 0, 0, 0);        \
      }                                                                               \
      _Pragma("unroll")                                                               \
      for (int r = 0; r < 4; ++r) upd(mg[r], sg[r], accg[r]);                         \
    } else {                                                                          \
      _Pragma("unroll")                                                               \
      for (int k = 0; k < 8; ++k) {                                                   \
        const short8 bf = *(const short8*)(qb + l15 * 512 + ((((k * 4 + l4) ^ l15) & 31) << 4)); \
        acc0 = __builtin_amdgcn_mfma_f32_16x16x32_bf16(afrag[0][k], bf, acc0, 0, 0, 0); \
        acc1 = __builtin_amdgcn_mfma_f32_16x16x32_bf16(afrag[1][k], bf, acc1, 0, 0, 0); \
      }                                                                               \
    }                                                                                 \
    _Pragma("unroll")                                                                 \
    for (int r = 0; r < 4; ++r) upd(mz[0][r], sz[0][r], acc0[r]);                     \
    _Pragma("unroll")                                                                 \
    for (int r = 0; r < 4; ++r) upd(mz[1][r], sz[1][r], acc1[r]);                     \
  }

  for (int st = 0; st < SUBT; st += 2) {
    // ---- body A: load tile st+2; write tile st+1 (buf1); compute tile st (buf0)
    if (st + 2 < SUBT) {
      const float* qp = qbase + (st + 2) * (16 * D_);
      fa0 = *(const float4*)qp;
      fa1 = *(const float4*)(qp + 4);
    }
    *(short8*)(qs[1] + woff) = cvt8(fb0, fb1);
    COMPUTE(0, st)
    __syncthreads();

    // ---- body B: load tile st+3; write tile st+2 (buf0); compute tile st+1 (buf1)
    if (st + 3 < SUBT) {
      const float* qp = qbase + (st + 3) * (16 * D_);
      fb0 = *(const float4*)qp;
      fb1 = *(const float4*)(qp + 4);
    }
    if (st + 2 < SUBT) *(short8*)(qs[0] + woff) = cvt8(fa0, fa1);
    COMPUTE(1, st + 1)
    __syncthreads();
  }

  // merge across the 16 column-lanes
#pragma unroll
  for (int s = 0; s < 2; ++s)
#pragma unroll
    for (int r = 0; r < 4; ++r) {
#pragma unroll
      for (int mask = 1; mask < 16; mask <<= 1) {
        const float om = __shfl_xor(mz[s][r], mask);
        const float os = __shfl_xor(sz[s][r], mask);
        merge_ms(mz[s][r], sz[s][r], om, os);
      }
    }

  if (l15 == 0) {
#pragma unroll
    for (int s = 0; s < 2; ++s)
#pragma unroll
      for (int r = 0; r < 4; ++r) {
        const int row = rowgroup * 256 + wid * 32 + s * 16 + l4 * 4 + r;
        zpart[row * NBLK + chunk] = make_float2(mz[s][r], sz[s][r]);
      }
  }

  if (dog) {
#pragma unroll
    for (int r = 0; r < 4; ++r) {
#pragma unroll
      for (int mask = 1; mask < 16; mask <<= 1) {
        const float om = __shfl_xor(mg[r], mask);
        const float os = __shfl_xor(sg[r], mask);
        merge_ms(mg[r], sg[r], om, os);
      }
    }
    if (l15 == 0) {
#pragma unroll
      for (int r = 0; r < 4; ++r)
        gbuf[wid * 16 + l4 * 4 + r] = make_float2(mg[r], sg[r]);
    }
    __syncthreads();
    if (tid < 16) {
      float m = gbuf[tid].x, s = gbuf[tid].y;
      for (int w = 1; w < 8; ++w) merge_ms(m, s, gbuf[w * 16 + tid].x, gbuf[w * 16 + tid].y);
      gpart[tid * NBLK + chunk] = make_float2(m, s);
    }
  }
}

// ---------------- zmm: masked lse over the 512 z columns via MFMA + pos extraction ----
__global__ __launch_bounds__(512) void zmm_kernel(
    const short* __restrict__ Abf, const short* __restrict__ Zp,
    float2* __restrict__ zcol, float* __restrict__ posll, float* __restrict__ posgl) {
  const int tid = threadIdx.x;
  const int wid = tid >> 6, lane = tid & 63;
  const int l15 = lane & 15, l4 = lane >> 4;
  const int r0 = blockIdx.x * 16;

  short8 af[8];
#pragma unroll
  for (int k = 0; k < 8; ++k)
    af[k] = *(const short8*)(Abf + (r0 + l15) * D_ + l4 * 8 + k * 32);

  float m[4], s[4];
#pragma unroll
  for (int r = 0; r < 4; ++r) { m[r] = -1e30f; s[r] = 0.f; }

  for (int st = 0; st < 4; ++st) {
    const int c0 = wid * 64 + st * 16;
    const f32x4 fz = {0.f, 0.f, 0.f, 0.f};
    f32x4 acc = fz;
#pragma unroll
    for (int k = 0; k < 8; ++k) {
      const short8 bq = *(const short8*)(Zp + (c0 + l15) * D_ + l4 * 8 + k * 32);
      acc = __builtin_amdgcn_mfma_f32_16x16x32_bf16(af[k], bq, acc, 0, 0, 0);
    }
#pragma unroll
    for (int r = 0; r < 4; ++r) {
      const int row = r0 + l4 * 4 + r;
      const int col = c0 + l15;
      const float v = acc[r];
      bool masked;
      if (r0 < NROWS_Z) {
        if (col == row + 1) posll[row] = v * LN2;
        masked = (col == row) || (col == row + 1);
      } else {
        const int b = row - NROWS_Z;
        const bool own = ((col >> 5) == b);
        if (own) posgl[col] = v * LN2;
        masked = own;
      }
      if (!masked) upd(m[r], s[r], v);
    }
  }
#pragma unroll
  for (int r = 0; r < 4; ++r) {
#pragma unroll
    for (int mask = 1; mask < 16; mask <<= 1) {
      const float om = __shfl_xor(m[r], mask);
      const float os = __shfl_xor(s[r], mask);
      merge_ms(m[r], s[r], om, os);
    }
  }
  __shared__ float2 lds[8][16];
  if (l15 == 0) {
#pragma unroll
    for (int r = 0; r < 4; ++r) lds[wid][l4 * 4 + r] = make_float2(m[r], s[r]);
  }
  __syncthreads();
  if (tid < 16) {
    float mm = lds[0][tid].x, ss = lds[0][tid].y;
    for (int w = 1; w < 8; ++w) merge_ms(mm, ss, lds[w][tid].x, lds[w][tid].y);
    zcol[r0 + tid] = make_float2(mm, ss);
  }
}

// ---------------- reduce: merge 256 chunk partials + zcol partial per row ----------------
__global__ void reduce_kernel(const float2* __restrict__ zpart, const float2* __restrict__ gpart,
                              const float2* __restrict__ zcol, float* __restrict__ lse_row) {
  const int r = blockIdx.x, tid = threadIdx.x;
  const float2 p = (r < NROWS_Z) ? zpart[r * NBLK + tid] : gpart[(r - NROWS_Z) * NBLK + tid];
  float m = p.x, s = p.y;
  __shared__ float2 red[4];
#pragma unroll
  for (int mask = 1; mask < 64; mask <<= 1) {
    const float om = __shfl_xor(m, mask);
    const float os = __shfl_xor(s, mask);
    merge_ms(m, s, om, os);
  }
  if ((tid & 63) == 0) red[tid >> 6] = make_float2(m, s);
  __syncthreads();
  if (tid == 0) {
    for (int w = 1; w < 4; ++w) merge_ms(m, s, red[w].x, red[w].y);
    const float2 zc = zcol[r];
    merge_ms(m, s, zc.x, zc.y);
    lse_row[r] = LN2 * (m + log2fast(s));   // back to natural log
  }
}

// ---------------- final: losses ----------------
__global__ void final_kernel(const float* __restrict__ lse_row, const float* __restrict__ posll,
                             const float* __restrict__ posgl, const float* __restrict__ smoothp,
                             float* __restrict__ out) {
  const int tid = threadIdx.x;
  float a_ll = 0.f, a_gl = 0.f, a_sm = 0.f;
  for (int i = tid; i < 496; i += 256) {
    const int b = i / 31, t = i - b * 31;
    const int a = b * 32 + t;
    const float pos = posll[a], lse = lse_row[a];
    const float d = lse - pos;
    a_ll += (d > 0.f) ? d + log1pf(__expf(-d)) : log1pf(__expf(d));
  }
  for (int i = tid; i < 512; i += 256) {
    const float pos = posgl[i], lse = lse_row[NROWS_Z + (i >> 5)];
    const float d = lse - pos;
    a_gl += (d > 0.f) ? d + log1pf(__expf(-d)) : log1pf(__expf(d));
  }
  for (int i = tid; i < 512; i += 256) a_sm += smoothp[i];

  __shared__ float red[4];
  float sums[3] = {a_ll, a_gl, a_sm};
  float tot[3];
  for (int j = 0; j < 3; ++j) {
    float v = sums[j];
#pragma unroll
    for (int mask = 1; mask < 64; mask <<= 1) v += __shfl_xor(v, mask);
    __syncthreads();
    if ((tid & 63) == 0) red[tid >> 6] = v;
    __syncthreads();
    tot[j] = red[0] + red[1] + red[2] + red[3];
  }
  if (tid == 0)
    out[0] = tot[0] / 496.f + 0.5f * (tot[1] / 512.f) + 0.1f * (tot[2] / 496.f);
}

extern "C" void kernel_launch(void* const* d_in, const int* in_sizes, int n_in,
                              void* d_out, int out_size, void* d_ws, size_t ws_size,
                              hipStream_t stream) {
  const float* z = (const float*)d_in[0];      // [512,256]
  const float* g = (const float*)d_in[1];      // [16,256]
  const float* queue = (const float*)d_in[3];  // [131072,256]
  float* out = (float*)d_out;
  char* ws = (char*)d_ws;

  constexpr size_t OFF_A = 0;                         // 528*256*2 = 270336
  constexpr size_t OFF_ZP = OFF_A + 270336;           // 512*256*2 = 262144
  constexpr size_t OFF_ZPART = OFF_ZP + 262144;       // 512*256*8 = 1048576
  constexpr size_t OFF_GPART = OFF_ZPART + 1048576;   // 16*256*8  = 32768
  constexpr size_t OFF_ZCOL = OFF_GPART + 32768;      // 528*8     = 4224
  constexpr size_t OFF_POSLL = OFF_ZCOL + 4224;       // 512*4
  constexpr size_t OFF_POSGL = OFF_POSLL + 2048;      // 512*4
  constexpr size_t OFF_SM = OFF_POSGL + 2048;         // 512*4
  constexpr size_t OFF_LSE = OFF_SM + 2048;           // 528*4

  short* Abf = (short*)(ws + OFF_A);
  short* Zp = (short*)(ws + OFF_ZP);
  float2* zpart = (float2*)(ws + OFF_ZPART);
  float2* gpart = (float2*)(ws + OFF_GPART);
  float2* zcol = (float2*)(ws + OFF_ZCOL);
  float* posll = (float*)(ws + OFF_POSLL);
  float* posgl = (float*)(ws + OFF_POSGL);
  float* smoothp = (float*)(ws + OFF_SM);
  float* lse_row = (float*)(ws + OFF_LSE);

  prep_kernel<<<NROWS, 256, 0, stream>>>(z, g, Abf, Zp, smoothp);
  big_kernel<<<NBLK_BIG, 512, 0, stream>>>(queue, Abf, zpart, gpart);
  zmm_kernel<<<33, 512, 0, stream>>>(Abf, Zp, zcol, posll, posgl);
  reduce_kernel<<<NROWS, 256, 0, stream>>>(zpart, gpart, zcol, lse_row);
  final_kernel<<<1, 256, 0, stream>>>(lse_row, posll, posgl, smoothp, out);
}

// Round 7
// 118.260 us; speedup vs baseline: 1.9254x; 1.0371x over previous
//
#include <hip/hip_runtime.h>
#include <hip/hip_bf16.h>

#define D_ 256
#define NROWS_Z 512
#define NROWS 528
#define KQ 131072
// (1/tau) * log2(e): logits computed directly in log2 domain
#define SCALE_A 20.6099291041f
#define INV_SCALE_A (1.0f / SCALE_A)
#define LN2 0.6931471805599453f

typedef __attribute__((ext_vector_type(8))) short short8;
typedef __attribute__((ext_vector_type(4))) float f32x4;

__device__ __forceinline__ float exp2fast(float x) {
  float r; asm("v_exp_f32 %0, %1" : "=v"(r) : "v"(x)); return r;
}
__device__ __forceinline__ float log2fast(float x) {
  float r; asm("v_log_f32 %0, %1" : "=v"(r) : "v"(x)); return r;
}

__device__ __forceinline__ short bf16r(float x) {
  union { float f; unsigned u; } c; c.f = x;
  unsigned r = (c.u + 0x7fffu + ((c.u >> 16) & 1u)) >> 16;  // RNE
  return (short)r;
}

// two floats -> two fp8 e4m3 (RNE, saturating) in low 16 bits
__device__ __forceinline__ unsigned cvt2fp8(float a, float b) {
  unsigned r;
  asm("v_cvt_pk_fp8_f32 %0, %1, %2" : "=v"(r) : "v"(a), "v"(b));
  return r & 0xFFFFu;
}

// merge two (max, sum2^) lse states, log2 domain
__device__ __forceinline__ void merge_ms(float& m, float& s, float m2, float s2) {
  float mm = fmaxf(m, m2);
  s = s * exp2fast(m - mm) + s2 * exp2fast(m2 - mm);
  m = mm;
}

// T13 defer-max online update: wave-uniform rescale branch, 1 trans common path
__device__ __forceinline__ void upd(float& m, float& s, float v) {
  float d = v - m;
  if (__builtin_expect(__any(d > 8.f), 0)) {
    const float mn = fmaxf(m, v);
    s *= exp2fast(m - mn);
    m = mn; d = v - m;
  }
  s += exp2fast(d);
}

// ---------------- prep: Abf16[528][256] (scaled, for zmm), Abf8[528][256]
// ---------------- (scaled fp8, for big), per-row smoothness partials ----------------
__global__ void prep_kernel(const float* __restrict__ z, const float* __restrict__ g,
                            short* __restrict__ Abf, char* __restrict__ Abf8,
                            float* __restrict__ smoothp) {
  const int r = blockIdx.x, d = threadIdx.x;
  __shared__ float vals[256];
  __shared__ float red[4];
  const float v = (r < NROWS_Z) ? z[r * D_ + d] : g[(r - NROWS_Z) * D_ + d];
  const float vs = v * SCALE_A;
  Abf[r * D_ + d] = bf16r(vs);
  vals[d] = vs;
  float acc = 0.f;
  if (r < NROWS_Z && (r & 31) != 31) { const float dv = z[(r + 1) * D_ + d] - v; acc = dv * dv; }
#pragma unroll
  for (int mask = 1; mask < 64; mask <<= 1) acc += __shfl_xor(acc, mask);
  if ((d & 63) == 0) red[d >> 6] = acc;
  __syncthreads();
  if (d < 64) {
    const float4 q = *(const float4*)(vals + d * 4);
    const unsigned w = cvt2fp8(q.x, q.y) | (cvt2fp8(q.z, q.w) << 16);
    *(unsigned*)(Abf8 + r * D_ + d * 4) = w;
  }
  if (d == 0 && r < NROWS_Z) smoothp[r] = red[0] + red[1] + red[2] + red[3];
}

// ---------------- big: per-row online lse over 131072 queue columns (fp8 MFMA) -------
// nchunk blocks; 8 waves x 64 z-rows register-resident (fp8 afrag = 64 VGPR).
// g handled by rotating wave: mfma(A=staged queue tile, B=g^T) reusing the same bytes.
__global__ __launch_bounds__(512, 2) void big_kernel(
    const float* __restrict__ queue, const char* __restrict__ Abf8,
    float2* __restrict__ zpart, float2* __restrict__ gpart,
    int nchunk, int subt) {
  const int tid = threadIdx.x, blk = blockIdx.x;
  const int wid = tid >> 6, lane = tid & 63;
  const int l15 = lane & 15, l4 = lane >> 4;
  const int qrows = KQ / nchunk;

  __shared__ __align__(16) char qs[2][16 * 256];  // 2 x (16 qrows x 256 fp8), swizzled
  __shared__ float2 gbuf[8][16];

  // A fragments resident: 4 slabs x 8 ksteps x 8B = 64 VGPR
  long afrag[4][8];
#pragma unroll
  for (int s = 0; s < 4; ++s) {
    const char* base = Abf8 + (wid * 64 + s * 16 + l15) * D_ + l4 * 8;
#pragma unroll
    for (int k = 0; k < 8; ++k) afrag[s][k] = *(const long*)(base + k * 32);
  }
  const char* gBbase = Abf8 + (NROWS_Z + l15) * D_ + l4 * 8;

  float mz[4][4], sz[4][4];
#pragma unroll
  for (int s = 0; s < 4; ++s)
#pragma unroll
    for (int r = 0; r < 4; ++r) { mz[s][r] = -1e30f; sz[s][r] = 0.f; }
  float mg = -1e30f, sg = 0.f;  // per-lane: g-col l15, qrows of this lane's l4 group

  const int srow = tid >> 5;      // 16 staging rows, 32 threads each
  const int sslot = tid & 31;     // 8B slot within row
  const int woff = srow * D_ + ((sslot ^ srow) << 3);
  const float* qbase = queue + (size_t)(blk * qrows + srow) * D_ + sslot * 8;

  const f32x4 fz = {0.f, 0.f, 0.f, 0.f};

#define STAGE(BUF)                                                                    \
  {                                                                                   \
    const unsigned w0 = cvt2fp8(fa0.x, fa0.y) | (cvt2fp8(fa0.z, fa0.w) << 16);        \
    const unsigned w1 = cvt2fp8(fa1.x, fa1.y) | (cvt2fp8(fa1.z, fa1.w) << 16);        \
    *(uint2*)(qs[BUF] + woff) = make_uint2(w0, w1);                                   \
  }

#define COMPUTE(BUF, ST)                                                              \
  {                                                                                   \
    const char* qb = qs[BUF];                                                         \
    f32x4 acc0 = fz, acc1 = fz, acc2 = fz, acc3 = fz;                                 \
    _Pragma("unroll")                                                                 \
    for (int kk = 0; kk < 8; ++kk) {                                                  \
      const long bf = *(const long*)(qb + l15 * D_ + (((kk * 4 + l4) ^ l15) << 3));   \
      acc0 = __builtin_amdgcn_mfma_f32_16x16x32_fp8_fp8(afrag[0][kk], bf, acc0, 0, 0, 0); \
      acc1 = __builtin_amdgcn_mfma_f32_16x16x32_fp8_fp8(afrag[1][kk], bf, acc1, 0, 0, 0); \
      acc2 = __builtin_amdgcn_mfma_f32_16x16x32_fp8_fp8(afrag[2][kk], bf, acc2, 0, 0, 0); \
      acc3 = __builtin_amdgcn_mfma_f32_16x16x32_fp8_fp8(afrag[3][kk], bf, acc3, 0, 0, 0); \
    }                                                                                 \
    _Pragma("unroll")                                                                 \
    for (int r = 0; r < 4; ++r) {                                                     \
      upd(mz[0][r], sz[0][r], acc0[r]);                                               \
      upd(mz[1][r], sz[1][r], acc1[r]);                                               \
      upd(mz[2][r], sz[2][r], acc2[r]);                                               \
      upd(mz[3][r], sz[3][r], acc3[r]);                                               \
    }                                                                                 \
    if ((((ST) & 7)) == wid) {                                                        \
      f32x4 accg = fz;                                                                \
      _Pragma("unroll")                                                               \
      for (int kk = 0; kk < 8; ++kk) {                                                \
        const long bf = *(const long*)(qb + l15 * D_ + (((kk * 4 + l4) ^ l15) << 3)); \
        const long gb = *(const long*)(gBbase + kk * 32);                             \
        accg = __builtin_amdgcn_mfma_f32_16x16x32_fp8_fp8(bf, gb, accg, 0, 0, 0);     \
      }                                                                               \
      _Pragma("unroll")                                                               \
      for (int r = 0; r < 4; ++r) upd(mg, sg, accg[r]);                               \
    }                                                                                 \
  }

  // prologue: stage tile 0
  float4 fa0 = *(const float4*)qbase;
  float4 fa1 = *(const float4*)(qbase + 4);
  STAGE(0)
  __syncthreads();

  for (int st = 0; st < subt; st += 2) {
    // body A: load tile st+1; compute tile st (buf0); write tile st+1 (buf1)
    {
      const float* qp = qbase + (size_t)(st + 1) * (16 * D_);
      fa0 = *(const float4*)qp;
      fa1 = *(const float4*)(qp + 4);
    }
    COMPUTE(0, st)
    STAGE(1)
    __syncthreads();

    // body B: load tile st+2; compute tile st+1 (buf1); write tile st+2 (buf0)
    if (st + 2 < subt) {
      const float* qp = qbase + (size_t)(st + 2) * (16 * D_);
      fa0 = *(const float4*)qp;
      fa1 = *(const float4*)(qp + 4);
    }
    COMPUTE(1, st + 1)
    if (st + 2 < subt) STAGE(0)
    __syncthreads();
  }

  // merge z-lse across the 16 column-lanes
#pragma unroll
  for (int s = 0; s < 4; ++s)
#pragma unroll
    for (int r = 0; r < 4; ++r) {
#pragma unroll
      for (int mask = 1; mask < 16; mask <<= 1) {
        const float om = __shfl_xor(mz[s][r], mask);
        const float os = __shfl_xor(sz[s][r], mask);
        merge_ms(mz[s][r], sz[s][r], om, os);
      }
    }
  if (l15 == 0) {
#pragma unroll
    for (int s = 0; s < 4; ++s)
#pragma unroll
      for (int r = 0; r < 4; ++r) {
        const int row = wid * 64 + s * 16 + l4 * 4 + r;
        zpart[row * nchunk + blk] = make_float2(mz[s][r], sz[s][r]);
      }
  }

  // merge g-lse across the 4 l4-groups (lanes differing in bits 4,5)
#pragma unroll
  for (int mask = 16; mask < 64; mask <<= 1) {
    const float om = __shfl_xor(mg, mask);
    const float os = __shfl_xor(sg, mask);
    merge_ms(mg, sg, om, os);
  }
  if (lane < 16) gbuf[wid][l15] = make_float2(mg, sg);
  __syncthreads();
  if (tid < 16) {
    float m = gbuf[0][tid].x, s = gbuf[0][tid].y;
    for (int w = 1; w < 8; ++w) merge_ms(m, s, gbuf[w][tid].x, gbuf[w][tid].y);
    gpart[tid * nchunk + blk] = make_float2(m, s);
  }
}

// ---------------- zmm: masked lse over the 512 z columns via bf16 MFMA ----------------
// Uses scaled Abf for BOTH operands; acc * (1/SCALE_A) restores log2-logit units.
__global__ __launch_bounds__(512) void zmm_kernel(
    const short* __restrict__ Abf,
    float2* __restrict__ zcol, float* __restrict__ posll, float* __restrict__ posgl) {
  const int tid = threadIdx.x;
  const int wid = tid >> 6, lane = tid & 63;
  const int l15 = lane & 15, l4 = lane >> 4;
  const int r0 = blockIdx.x * 16;

  short8 af[8];
#pragma unroll
  for (int k = 0; k < 8; ++k)
    af[k] = *(const short8*)(Abf + (r0 + l15) * D_ + l4 * 8 + k * 32);

  float m[4], s[4];
#pragma unroll
  for (int r = 0; r < 4; ++r) { m[r] = -1e30f; s[r] = 0.f; }

  for (int st = 0; st < 4; ++st) {
    const int c0 = wid * 64 + st * 16;
    const f32x4 fz = {0.f, 0.f, 0.f, 0.f};
    f32x4 acc = fz;
#pragma unroll
    for (int k = 0; k < 8; ++k) {
      const short8 bq = *(const short8*)(Abf + (c0 + l15) * D_ + l4 * 8 + k * 32);
      acc = __builtin_amdgcn_mfma_f32_16x16x32_bf16(af[k], bq, acc, 0, 0, 0);
    }
#pragma unroll
    for (int r = 0; r < 4; ++r) {
      const int row = r0 + l4 * 4 + r;
      const int col = c0 + l15;
      const float v = acc[r] * INV_SCALE_A;  // log2-logit
      bool masked;
      if (r0 < NROWS_Z) {
        if (col == row + 1) posll[row] = v * LN2;
        masked = (col == row) || (col == row + 1);
      } else {
        const int b = row - NROWS_Z;
        const bool own = ((col >> 5) == b);
        if (own) posgl[col] = v * LN2;
        masked = own;
      }
      if (!masked) upd(m[r], s[r], v);
    }
  }
#pragma unroll
  for (int r = 0; r < 4; ++r) {
#pragma unroll
    for (int mask = 1; mask < 16; mask <<= 1) {
      const float om = __shfl_xor(m[r], mask);
      const float os = __shfl_xor(s[r], mask);
      merge_ms(m[r], s[r], om, os);
    }
  }
  __shared__ float2 lds[8][16];
  if (l15 == 0) {
#pragma unroll
    for (int r = 0; r < 4; ++r) lds[wid][l4 * 4 + r] = make_float2(m[r], s[r]);
  }
  __syncthreads();
  if (tid < 16) {
    float mm = lds[0][tid].x, ss = lds[0][tid].y;
    for (int w = 1; w < 8; ++w) merge_ms(mm, ss, lds[w][tid].x, lds[w][tid].y);
    zcol[r0 + tid] = make_float2(mm, ss);
  }
}

// ---------------- reduce: merge nchunk partials + zcol partial per row ----------------
__global__ void reduce_kernel(const float2* __restrict__ zpart, const float2* __restrict__ gpart,
                              const float2* __restrict__ zcol, float* __restrict__ lse_row,
                              int nchunk) {
  const int r = blockIdx.x, tid = threadIdx.x;
  const float2 p = (r < NROWS_Z) ? zpart[r * nchunk + tid] : gpart[(r - NROWS_Z) * nchunk + tid];
  float m = p.x, s = p.y;
  __shared__ float2 red[8];
#pragma unroll
  for (int mask = 1; mask < 64; mask <<= 1) {
    const float om = __shfl_xor(m, mask);
    const float os = __shfl_xor(s, mask);
    merge_ms(m, s, om, os);
  }
  if ((tid & 63) == 0) red[tid >> 6] = make_float2(m, s);
  __syncthreads();
  if (tid == 0) {
    const int nw = blockDim.x >> 6;
    for (int w = 1; w < nw; ++w) merge_ms(m, s, red[w].x, red[w].y);
    const float2 zc = zcol[r];
    merge_ms(m, s, zc.x, zc.y);
    lse_row[r] = LN2 * (m + log2fast(s));   // back to natural log
  }
}

// ---------------- final: losses ----------------
__global__ void final_kernel(const float* __restrict__ lse_row, const float* __restrict__ posll,
                             const float* __restrict__ posgl, const float* __restrict__ smoothp,
                             float* __restrict__ out) {
  const int tid = threadIdx.x;
  float a_ll = 0.f, a_gl = 0.f, a_sm = 0.f;
  for (int i = tid; i < 496; i += 256) {
    const int b = i / 31, t = i - b * 31;
    const int a = b * 32 + t;
    const float pos = posll[a], lse = lse_row[a];
    const float d = lse - pos;
    a_ll += (d > 0.f) ? d + log1pf(__expf(-d)) : log1pf(__expf(d));
  }
  for (int i = tid; i < 512; i += 256) {
    const float pos = posgl[i], lse = lse_row[NROWS_Z + (i >> 5)];
    const float d = lse - pos;
    a_gl += (d > 0.f) ? d + log1pf(__expf(-d)) : log1pf(__expf(d));
  }
  for (int i = tid; i < 512; i += 256) a_sm += smoothp[i];

  __shared__ float red[4];
  float sums[3] = {a_ll, a_gl, a_sm};
  float tot[3];
  for (int j = 0; j < 3; ++j) {
    float v = sums[j];
#pragma unroll
    for (int mask = 1; mask < 64; mask <<= 1) v += __shfl_xor(v, mask);
    __syncthreads();
    if ((tid & 63) == 0) red[tid >> 6] = v;
    __syncthreads();
    tot[j] = red[0] + red[1] + red[2] + red[3];
  }
  if (tid == 0)
    out[0] = tot[0] / 496.f + 0.5f * (tot[1] / 512.f) + 0.1f * (tot[2] / 496.f);
}

extern "C" void kernel_launch(void* const* d_in, const int* in_sizes, int n_in,
                              void* d_out, int out_size, void* d_ws, size_t ws_size,
                              hipStream_t stream) {
  const float* z = (const float*)d_in[0];      // [512,256]
  const float* g = (const float*)d_in[1];      // [16,256]
  const float* queue = (const float*)d_in[3];  // [131072,256]
  float* out = (float*)d_out;
  char* ws = (char*)d_ws;

  // workspace layout (nchunk-dependent); fall back to 256 chunks if ws is small
  const size_t offA = 0;                     // 528*256*2 = 270336
  const size_t offA8 = 270336;               // 528*256   = 135168
  const size_t offZpart = offA8 + 135168;    // 512*nchunk*8
  auto need = [&](int nc) -> size_t {
    return offZpart + (size_t)512 * nc * 8 + (size_t)16 * nc * 8 + 4224 + 2048 + 2048 + 2048 + 2112;
  };
  const int nchunk = (ws_size >= need(512)) ? 512 : 256;
  const int subt = (KQ / nchunk) / 16;

  const size_t offGpart = offZpart + (size_t)512 * nchunk * 8;
  const size_t offZcol = offGpart + (size_t)16 * nchunk * 8;
  const size_t offPosll = offZcol + 4224;
  const size_t offPosgl = offPosll + 2048;
  const size_t offSm = offPosgl + 2048;
  const size_t offLse = offSm + 2048;

  short* Abf = (short*)(ws + offA);
  char* Abf8 = (char*)(ws + offA8);
  float2* zpart = (float2*)(ws + offZpart);
  float2* gpart = (float2*)(ws + offGpart);
  float2* zcol = (float2*)(ws + offZcol);
  float* posll = (float*)(ws + offPosll);
  float* posgl = (float*)(ws + offPosgl);
  float* smoothp = (float*)(ws + offSm);
  float* lse_row = (float*)(ws + offLse);

  prep_kernel<<<NROWS, 256, 0, stream>>>(z, g, Abf, Abf8, smoothp);
  big_kernel<<<nchunk, 512, 0, stream>>>(queue, Abf8, zpart, gpart, nchunk, subt);
  zmm_kernel<<<33, 512, 0, stream>>>(Abf, zcol, posll, posgl);
  reduce_kernel<<<NROWS, nchunk, 0, stream>>>(zpart, gpart, zcol, lse_row, nchunk);
  final_kernel<<<1, 256, 0, stream>>>(lse_row, posll, posgl, smoothp, out);
}

// Round 8
// 103.265 us; speedup vs baseline: 2.2050x; 1.1452x over previous
//
#include <hip/hip_runtime.h>
#include <hip/hip_bf16.h>

#define D_ 256
#define NROWS_Z 512
#define NROWS 528
#define KQ 131072
#define NCHUNK 256
#define QR 512              // queue rows per chunk
#define PH 16               // phases per block (32 qrows each)
// (1/tau) * log2(e): logits computed directly in log2 domain
#define SCALE_A 20.6099291041f
#define INV_SCALE_A (1.0f / SCALE_A)
#define LN2 0.6931471805599453f

typedef __attribute__((ext_vector_type(8))) short short8;
typedef __attribute__((ext_vector_type(4))) float f32x4;

__device__ __forceinline__ float exp2fast(float x) {
  float r; asm("v_exp_f32 %0, %1" : "=v"(r) : "v"(x)); return r;
}
__device__ __forceinline__ float log2fast(float x) {
  float r; asm("v_log_f32 %0, %1" : "=v"(r) : "v"(x)); return r;
}

__device__ __forceinline__ short bf16r(float x) {
  union { float f; unsigned u; } c; c.f = x;
  unsigned r = (c.u + 0x7fffu + ((c.u >> 16) & 1u)) >> 16;  // RNE
  return (short)r;
}

// two floats -> two fp8 e4m3 (RNE, saturating) in low 16 bits
__device__ __forceinline__ unsigned cvt2fp8(float a, float b) {
  unsigned r;
  asm("v_cvt_pk_fp8_f32 %0, %1, %2" : "=v"(r) : "v"(a), "v"(b));
  return r & 0xFFFFu;
}

// merge two (max, sum2^) lse states, log2 domain
__device__ __forceinline__ void merge_ms(float& m, float& s, float m2, float s2) {
  float mm = fmaxf(m, m2);
  s = s * exp2fast(m - mm) + s2 * exp2fast(m2 - mm);
  m = mm;
}

// T13 defer-max online update: wave-uniform rescale branch, 1 trans common path
__device__ __forceinline__ void upd(float& m, float& s, float v) {
  float d = v - m;
  if (__builtin_expect(__any(d > 8.f), 0)) {
    const float mn = fmaxf(m, v);
    s *= exp2fast(m - mn);
    m = mn; d = v - m;
  }
  s += exp2fast(d);
}

// ---------------- prep: Abf16[528][256] (scaled, zmm), Abf8[528][256] (scaled fp8,
// ---------------- big), per-row smoothness partials ----------------
__global__ void prep_kernel(const float* __restrict__ z, const float* __restrict__ g,
                            short* __restrict__ Abf, char* __restrict__ Abf8,
                            float* __restrict__ smoothp) {
  const int r = blockIdx.x, d = threadIdx.x;
  __shared__ float vals[256];
  __shared__ float red[4];
  const float v = (r < NROWS_Z) ? z[r * D_ + d] : g[(r - NROWS_Z) * D_ + d];
  const float vs = v * SCALE_A;
  Abf[r * D_ + d] = bf16r(vs);
  vals[d] = vs;
  float acc = 0.f;
  if (r < NROWS_Z && (r & 31) != 31) { const float dv = z[(r + 1) * D_ + d] - v; acc = dv * dv; }
#pragma unroll
  for (int mask = 1; mask < 64; mask <<= 1) acc += __shfl_xor(acc, mask);
  if ((d & 63) == 0) red[d >> 6] = acc;
  __syncthreads();
  if (d < 64) {
    const float4 q = *(const float4*)(vals + d * 4);
    const unsigned w = cvt2fp8(q.x, q.y) | (cvt2fp8(q.z, q.w) << 16);
    *(unsigned*)(Abf8 + r * D_ + d * 4) = w;
  }
  if (d == 0 && r < NROWS_Z) smoothp[r] = red[0] + red[1] + red[2] + red[3];
}

// ---------------- big: per-row online lse over 131072 queue columns (fp8 MFMA) -------
// 512 blocks = 2 rowgroups x 256 chunks (2 blocks/CU); 8 waves x 32 rows resident.
// Raw s_barrier + lgkmcnt(0) only (counted vmcnt survives the barrier -- T3/T4);
// 32-qrow phases, double-buffered. g rows: rotating wave, rowgroup-0 blocks only.
__global__ __launch_bounds__(512, 2) void big_kernel(
    const float* __restrict__ queue, const char* __restrict__ Abf8,
    float2* __restrict__ zpart, float2* __restrict__ gpart) {
  const int tid = threadIdx.x;
  const int chunk = blockIdx.x & 255;
  const int rg = blockIdx.x >> 8;           // 0: rows 0..255 (+g), 1: rows 256..511
  const int wid = tid >> 6, lane = tid & 63;
  const int l15 = lane & 15, l4 = lane >> 4;
  const int l4h = l4 >> 1;                  // 16B-slot half selector
  const int h8 = (l4 & 1) << 3;             // 8B offset within 16B slot

  __shared__ __align__(16) char qs[2][32 * 256];  // 2 x (32 qrows x 256 fp8), swizzled
  __shared__ float2 gbuf[8][16];

  // A fragments resident: 2 slabs x 8 ksteps x 8B = 32 VGPR
  long afrag[2][8];
#pragma unroll
  for (int s = 0; s < 2; ++s) {
    const char* base = Abf8 + (rg * 256 + wid * 32 + s * 16 + l15) * D_ + l4 * 8;
#pragma unroll
    for (int k = 0; k < 8; ++k) afrag[s][k] = *(const long*)(base + k * 32);
  }
  const char* gBbase = Abf8 + (NROWS_Z + l15) * D_ + l4 * 8;

  float mz[2][4], sz[2][4];
#pragma unroll
  for (int s = 0; s < 2; ++s)
#pragma unroll
    for (int r = 0; r < 4; ++r) { mz[s][r] = -1e30f; sz[s][r] = 0.f; }
  float mg = -1e30f, sg = 0.f;
  const bool dog = (rg == 0);

  // staging: 512 threads, each 16 fp8 bytes (16 floats) per phase
  const int srow = tid >> 4;       // 0..31 qrow within phase
  const int scol = tid & 15;       // 16B slot
  const int woff = srow * D_ + ((scol ^ (srow & 15)) << 4);
  const float* qbase = queue + (size_t)(chunk * QR + srow) * D_ + scol * 16;

  const f32x4 fz = {0.f, 0.f, 0.f, 0.f};

  float4 fa0, fa1, fa2, fa3, fb0, fb1, fb2, fb3;

#define LOADP(S0, S1, S2, S3, P)                                    \
  { const float4* qp = (const float4*)(qbase + (size_t)(P) * (32 * D_)); \
    S0 = qp[0]; S1 = qp[1]; S2 = qp[2]; S3 = qp[3]; }

#define CVTW(S0, S1, S2, S3, BUF)                                   \
  { const unsigned w0 = cvt2fp8(S0.x, S0.y) | (cvt2fp8(S0.z, S0.w) << 16); \
    const unsigned w1 = cvt2fp8(S1.x, S1.y) | (cvt2fp8(S1.z, S1.w) << 16); \
    const unsigned w2 = cvt2fp8(S2.x, S2.y) | (cvt2fp8(S2.z, S2.w) << 16); \
    const unsigned w3 = cvt2fp8(S3.x, S3.y) | (cvt2fp8(S3.z, S3.w) << 16); \
    *(uint4*)(qs[BUF] + woff) = make_uint4(w0, w1, w2, w3); }

  // write-visibility barrier WITHOUT vmcnt drain (prefetch stays in flight)
#define PBAR()                                                      \
  { asm volatile("s_waitcnt lgkmcnt(0)" ::: "memory");              \
    __builtin_amdgcn_sched_barrier(0);                              \
    __builtin_amdgcn_s_barrier(); }

  // one 16-row subtile: 8 ds_read_b64 + 16 MFMA + 8 upd (+ rotating g work)
#define CHALF(BUF, H, SIDX)                                         \
  { const char* qb = qs[BUF] + (H) * 16 * D_ + l15 * D_ + h8;       \
    f32x4 acc0 = fz, acc1 = fz;                                     \
    _Pragma("unroll")                                               \
    for (int kk = 0; kk < 8; ++kk) {                                \
      const long bf = *(const long*)(qb + ((((kk * 2 + l4h)) ^ l15) << 4)); \
      acc0 = __builtin_amdgcn_mfma_f32_16x16x32_fp8_fp8(afrag[0][kk], bf, acc0, 0, 0, 0); \
      acc1 = __builtin_amdgcn_mfma_f32_16x16x32_fp8_fp8(afrag[1][kk], bf, acc1, 0, 0, 0); \
    }                                                               \
    _Pragma("unroll")                                               \
    for (int r = 0; r < 4; ++r) { upd(mz[0][r], sz[0][r], acc0[r]); upd(mz[1][r], sz[1][r], acc1[r]); } \
    if (dog && (((SIDX) & 7) == wid)) {                             \
      f32x4 accg = fz;                                              \
      _Pragma("unroll")                                             \
      for (int kk = 0; kk < 8; ++kk) {                              \
        const long bf = *(const long*)(qb + ((((kk * 2 + l4h)) ^ l15) << 4)); \
        const long gb = *(const long*)(gBbase + kk * 32);           \
        accg = __builtin_amdgcn_mfma_f32_16x16x32_fp8_fp8(bf, gb, accg, 0, 0, 0); \
      }                                                             \
      _Pragma("unroll")                                             \
      for (int r = 0; r < 4; ++r) upd(mg, sg, accg[r]);             \
    } }

  // prologue: load P0,P1; stage P0; barrier (P1 loads remain in flight)
  LOADP(fa0, fa1, fa2, fa3, 0)
  LOADP(fb0, fb1, fb2, fb3, 1)
  CVTW(fa0, fa1, fa2, fa3, 0)
  PBAR()

  for (int i = 0; i < PH / 2; ++i) {
    const int t = 2 * i;
    // phase t (buf0): prefetch P(t+2); compute; stage P(t+1) -> buf1
    if (t + 2 < PH) LOADP(fa0, fa1, fa2, fa3, t + 2)
    CHALF(0, 0, t * 2)
    CHALF(0, 1, t * 2 + 1)
    CVTW(fb0, fb1, fb2, fb3, 1)
    PBAR()
    // phase t+1 (buf1): prefetch P(t+3); compute; stage P(t+2) -> buf0
    if (t + 3 < PH) LOADP(fb0, fb1, fb2, fb3, t + 3)
    CHALF(1, 0, t * 2 + 2)
    CHALF(1, 1, t * 2 + 3)
    if (t + 2 < PH) CVTW(fa0, fa1, fa2, fa3, 0)
    PBAR()
  }

  // merge z-lse across the 16 column-lanes
#pragma unroll
  for (int s = 0; s < 2; ++s)
#pragma unroll
    for (int r = 0; r < 4; ++r) {
#pragma unroll
      for (int mask = 1; mask < 16; mask <<= 1) {
        const float om = __shfl_xor(mz[s][r], mask);
        const float os = __shfl_xor(sz[s][r], mask);
        merge_ms(mz[s][r], sz[s][r], om, os);
      }
    }
  if (l15 == 0) {
#pragma unroll
    for (int s = 0; s < 2; ++s)
#pragma unroll
      for (int r = 0; r < 4; ++r) {
        const int row = rg * 256 + wid * 32 + s * 16 + l4 * 4 + r;
        zpart[row * NCHUNK + chunk] = make_float2(mz[s][r], sz[s][r]);
      }
  }

  if (dog) {
    // merge g-lse across the 4 l4-groups
#pragma unroll
    for (int mask = 16; mask < 64; mask <<= 1) {
      const float om = __shfl_xor(mg, mask);
      const float os = __shfl_xor(sg, mask);
      merge_ms(mg, sg, om, os);
    }
    if (lane < 16) gbuf[wid][l15] = make_float2(mg, sg);
    __syncthreads();
    if (tid < 16) {
      float m = gbuf[0][tid].x, s = gbuf[0][tid].y;
      for (int w = 1; w < 8; ++w) merge_ms(m, s, gbuf[w][tid].x, gbuf[w][tid].y);
      gpart[tid * NCHUNK + chunk] = make_float2(m, s);
    }
  }
}

// ---------------- zmm: masked lse over the 512 z columns via bf16 MFMA ----------------
__global__ __launch_bounds__(512) void zmm_kernel(
    const short* __restrict__ Abf,
    float2* __restrict__ zcol, float* __restrict__ posll, float* __restrict__ posgl) {
  const int tid = threadIdx.x;
  const int wid = tid >> 6, lane = tid & 63;
  const int l15 = lane & 15, l4 = lane >> 4;
  const int r0 = blockIdx.x * 16;

  short8 af[8];
#pragma unroll
  for (int k = 0; k < 8; ++k)
    af[k] = *(const short8*)(Abf + (r0 + l15) * D_ + l4 * 8 + k * 32);

  float m[4], s[4];
#pragma unroll
  for (int r = 0; r < 4; ++r) { m[r] = -1e30f; s[r] = 0.f; }

  for (int st = 0; st < 4; ++st) {
    const int c0 = wid * 64 + st * 16;
    const f32x4 fz = {0.f, 0.f, 0.f, 0.f};
    f32x4 acc = fz;
#pragma unroll
    for (int k = 0; k < 8; ++k) {
      const short8 bq = *(const short8*)(Abf + (c0 + l15) * D_ + l4 * 8 + k * 32);
      acc = __builtin_amdgcn_mfma_f32_16x16x32_bf16(af[k], bq, acc, 0, 0, 0);
    }
#pragma unroll
    for (int r = 0; r < 4; ++r) {
      const int row = r0 + l4 * 4 + r;
      const int col = c0 + l15;
      const float v = acc[r] * INV_SCALE_A;  // log2-logit
      bool masked;
      if (r0 < NROWS_Z) {
        if (col == row + 1) posll[row] = v * LN2;
        masked = (col == row) || (col == row + 1);
      } else {
        const int b = row - NROWS_Z;
        const bool own = ((col >> 5) == b);
        if (own) posgl[col] = v * LN2;
        masked = own;
      }
      if (!masked) upd(m[r], s[r], v);
    }
  }
#pragma unroll
  for (int r = 0; r < 4; ++r) {
#pragma unroll
    for (int mask = 1; mask < 16; mask <<= 1) {
      const float om = __shfl_xor(m[r], mask);
      const float os = __shfl_xor(s[r], mask);
      merge_ms(m[r], s[r], om, os);
    }
  }
  __shared__ float2 lds[8][16];
  if (l15 == 0) {
#pragma unroll
    for (int r = 0; r < 4; ++r) lds[wid][l4 * 4 + r] = make_float2(m[r], s[r]);
  }
  __syncthreads();
  if (tid < 16) {
    float mm = lds[0][tid].x, ss = lds[0][tid].y;
    for (int w = 1; w < 8; ++w) merge_ms(mm, ss, lds[w][tid].x, lds[w][tid].y);
    zcol[r0 + tid] = make_float2(mm, ss);
  }
}

// ---------------- reduce: merge 256 chunk partials + zcol partial per row ----------------
__global__ void reduce_kernel(const float2* __restrict__ zpart, const float2* __restrict__ gpart,
                              const float2* __restrict__ zcol, float* __restrict__ lse_row) {
  const int r = blockIdx.x, tid = threadIdx.x;
  const float2 p = (r < NROWS_Z) ? zpart[r * NCHUNK + tid] : gpart[(r - NROWS_Z) * NCHUNK + tid];
  float m = p.x, s = p.y;
  __shared__ float2 red[4];
#pragma unroll
  for (int mask = 1; mask < 64; mask <<= 1) {
    const float om = __shfl_xor(m, mask);
    const float os = __shfl_xor(s, mask);
    merge_ms(m, s, om, os);
  }
  if ((tid & 63) == 0) red[tid >> 6] = make_float2(m, s);
  __syncthreads();
  if (tid == 0) {
    for (int w = 1; w < 4; ++w) merge_ms(m, s, red[w].x, red[w].y);
    const float2 zc = zcol[r];
    merge_ms(m, s, zc.x, zc.y);
    lse_row[r] = LN2 * (m + log2fast(s));   // back to natural log
  }
}

// ---------------- final: losses ----------------
__global__ void final_kernel(const float* __restrict__ lse_row, const float* __restrict__ posll,
                             const float* __restrict__ posgl, const float* __restrict__ smoothp,
                             float* __restrict__ out) {
  const int tid = threadIdx.x;
  float a_ll = 0.f, a_gl = 0.f, a_sm = 0.f;
  for (int i = tid; i < 496; i += 256) {
    const int b = i / 31, t = i - b * 31;
    const int a = b * 32 + t;
    const float pos = posll[a], lse = lse_row[a];
    const float d = lse - pos;
    a_ll += (d > 0.f) ? d + log1pf(__expf(-d)) : log1pf(__expf(d));
  }
  for (int i = tid; i < 512; i += 256) {
    const float pos = posgl[i], lse = lse_row[NROWS_Z + (i >> 5)];
    const float d = lse - pos;
    a_gl += (d > 0.f) ? d + log1pf(__expf(-d)) : log1pf(__expf(d));
  }
  for (int i = tid; i < 512; i += 256) a_sm += smoothp[i];

  __shared__ float red[4];
  float sums[3] = {a_ll, a_gl, a_sm};
  float tot[3];
  for (int j = 0; j < 3; ++j) {
    float v = sums[j];
#pragma unroll
    for (int mask = 1; mask < 64; mask <<= 1) v += __shfl_xor(v, mask);
    __syncthreads();
    if ((tid & 63) == 0) red[tid >> 6] = v;
    __syncthreads();
    tot[j] = red[0] + red[1] + red[2] + red[3];
  }
  if (tid == 0)
    out[0] = tot[0] / 496.f + 0.5f * (tot[1] / 512.f) + 0.1f * (tot[2] / 496.f);
}

extern "C" void kernel_launch(void* const* d_in, const int* in_sizes, int n_in,
                              void* d_out, int out_size, void* d_ws, size_t ws_size,
                              hipStream_t stream) {
  const float* z = (const float*)d_in[0];      // [512,256]
  const float* g = (const float*)d_in[1];      // [16,256]
  const float* queue = (const float*)d_in[3];  // [131072,256]
  float* out = (float*)d_out;
  char* ws = (char*)d_ws;

  const size_t offA = 0;                        // 528*256*2 = 270336
  const size_t offA8 = 270336;                  // 528*256   = 135168
  const size_t offZpart = offA8 + 135168;       // 512*256*8 = 1048576
  const size_t offGpart = offZpart + 1048576;   // 16*256*8  = 32768
  const size_t offZcol = offGpart + 32768;      // 528*8     = 4224
  const size_t offPosll = offZcol + 4224;
  const size_t offPosgl = offPosll + 2048;
  const size_t offSm = offPosgl + 2048;
  const size_t offLse = offSm + 2048;

  short* Abf = (short*)(ws + offA);
  char* Abf8 = (char*)(ws + offA8);
  float2* zpart = (float2*)(ws + offZpart);
  float2* gpart = (float2*)(ws + offGpart);
  float2* zcol = (float2*)(ws + offZcol);
  float* posll = (float*)(ws + offPosll);
  float* posgl = (float*)(ws + offPosgl);
  float* smoothp = (float*)(ws + offSm);
  float* lse_row = (float*)(ws + offLse);

  prep_kernel<<<NROWS, 256, 0, stream>>>(z, g, Abf, Abf8, smoothp);
  big_kernel<<<512, 512, 0, stream>>>(queue, Abf8, zpart, gpart);
  zmm_kernel<<<33, 512, 0, stream>>>(Abf, zcol, posll, posgl);
  reduce_kernel<<<NROWS, NCHUNK, 0, stream>>>(zpart, gpart, zcol, lse_row);
  final_kernel<<<1, 256, 0, stream>>>(lse_row, posll, posgl, smoothp, out);
}

// Round 9
// 102.316 us; speedup vs baseline: 2.2254x; 1.0093x over previous
//
#include <hip/hip_runtime.h>
#include <hip/hip_bf16.h>

#define D_ 256
#define NROWS_Z 512
#define NROWS 528
#define KQ 131072
#define NCHUNK 256
#define QR 512              // queue rows per chunk
#define PH 32               // phases per block (16 qrows each)
// (1/tau) * log2(e): logits computed directly in log2 domain
#define SCALE_A 20.6099291041f
#define INV_SCALE_A (1.0f / SCALE_A)
#define LN2 0.6931471805599453f

typedef __attribute__((ext_vector_type(8))) short short8;
typedef __attribute__((ext_vector_type(4))) float f32x4;

__device__ __forceinline__ float exp2fast(float x) {
  float r; asm("v_exp_f32 %0, %1" : "=v"(r) : "v"(x)); return r;
}
__device__ __forceinline__ float log2fast(float x) {
  float r; asm("v_log_f32 %0, %1" : "=v"(r) : "v"(x)); return r;
}

__device__ __forceinline__ short bf16r(float x) {
  union { float f; unsigned u; } c; c.f = x;
  unsigned r = (c.u + 0x7fffu + ((c.u >> 16) & 1u)) >> 16;  // RNE
  return (short)r;
}

// two floats -> two fp8 e4m3 (RNE, saturating) in low 16 bits
__device__ __forceinline__ unsigned cvt2fp8(float a, float b) {
  unsigned r;
  asm("v_cvt_pk_fp8_f32 %0, %1, %2" : "=v"(r) : "v"(a), "v"(b));
  return r & 0xFFFFu;
}

// merge two (max, sum2^) lse states, log2 domain
__device__ __forceinline__ void merge_ms(float& m, float& s, float m2, float s2) {
  float mm = fmaxf(m, m2);
  s = s * exp2fast(m - mm) + s2 * exp2fast(m2 - mm);
  m = mm;
}

// T13 defer-max online update: wave-uniform rescale branch, 1 trans common path
__device__ __forceinline__ void upd(float& m, float& s, float v) {
  float d = v - m;
  if (__builtin_expect(__any(d > 8.f), 0)) {
    const float mn = fmaxf(m, v);
    s *= exp2fast(m - mn);
    m = mn; d = v - m;
  }
  s += exp2fast(d);
}

// ---------------- prep: Abf16[528][256] (scaled, zmm), Abf8[528][256] (scaled fp8,
// ---------------- big), per-row smoothness partials ----------------
__global__ void prep_kernel(const float* __restrict__ z, const float* __restrict__ g,
                            short* __restrict__ Abf, char* __restrict__ Abf8,
                            float* __restrict__ smoothp) {
  const int r = blockIdx.x, d = threadIdx.x;
  __shared__ float vals[256];
  __shared__ float red[4];
  const float v = (r < NROWS_Z) ? z[r * D_ + d] : g[(r - NROWS_Z) * D_ + d];
  const float vs = v * SCALE_A;
  Abf[r * D_ + d] = bf16r(vs);
  vals[d] = vs;
  float acc = 0.f;
  if (r < NROWS_Z && (r & 31) != 31) { const float dv = z[(r + 1) * D_ + d] - v; acc = dv * dv; }
#pragma unroll
  for (int mask = 1; mask < 64; mask <<= 1) acc += __shfl_xor(acc, mask);
  if ((d & 63) == 0) red[d >> 6] = acc;
  __syncthreads();
  if (d < 64) {
    const float4 q = *(const float4*)(vals + d * 4);
    const unsigned w = cvt2fp8(q.x, q.y) | (cvt2fp8(q.z, q.w) << 16);
    *(unsigned*)(Abf8 + r * D_ + d * 4) = w;
  }
  if (d == 0 && r < NROWS_Z) smoothp[r] = red[0] + red[1] + red[2] + red[3];
}

// ---------------- big: per-row online lse over 131072 queue columns (fp8 MFMA) -------
// 512 blocks = 2 rowgroups x 256 chunks, 256 threads (4 waves), 64 rows/wave fp8.
// Blocks j and j+256 share chunk j (256 % 8 == 0 -> same XCD, L2/L3 reuse).
// 2 blocks/CU co-resident: one block's barrier stalls overlap the other's compute.
__global__ __launch_bounds__(256) void big_kernel(
    const float* __restrict__ queue, const char* __restrict__ Abf8,
    float2* __restrict__ zpart, float2* __restrict__ gpart) {
  const int tid = threadIdx.x;
  const int chunk = blockIdx.x & 255;
  const int rg = blockIdx.x >> 8;           // 0: rows 0..255 (+g), 1: rows 256..511
  const int wid = tid >> 6, lane = tid & 63;
  const int l15 = lane & 15, l4 = lane >> 4;
  const int l4h = l4 >> 1;                  // 16B-slot half selector
  const int h8 = (l4 & 1) << 3;             // 8B offset within 16B slot

  __shared__ __align__(16) char qs[2][16 * 256];  // 2 x (16 qrows x 256 fp8), swizzled
  __shared__ float2 gbuf[4][16];

  // A fragments resident: 4 slabs x 8 ksteps x 8B = 64 VGPR
  long afrag[4][8];
#pragma unroll
  for (int s = 0; s < 4; ++s) {
    const char* base = Abf8 + (rg * 256 + wid * 64 + s * 16 + l15) * D_ + l4 * 8;
#pragma unroll
    for (int k = 0; k < 8; ++k) afrag[s][k] = *(const long*)(base + k * 32);
  }
  const char* gBbase = Abf8 + (NROWS_Z + l15) * D_ + l4 * 8;

  float mz[4][4], sz[4][4];
#pragma unroll
  for (int s = 0; s < 4; ++s)
#pragma unroll
    for (int r = 0; r < 4; ++r) { mz[s][r] = -1e30f; sz[s][r] = 0.f; }
  float mg = -1e30f, sg = 0.f;
  const bool dog = (rg == 0);

  // staging: 256 threads, 16 fp8 bytes (16 floats) each over 16 qrows x 256B
  const int srow = tid >> 4;       // 0..15 qrow within phase
  const int scol = tid & 15;       // 16B slot
  const int woff = srow * D_ + ((scol ^ srow) << 4);
  const float* qbase = queue + (size_t)(chunk * QR + srow) * D_ + scol * 16;

  const f32x4 fz = {0.f, 0.f, 0.f, 0.f};

  float4 fa0, fa1, fa2, fa3, fb0, fb1, fb2, fb3;

#define LOADP(S0, S1, S2, S3, P)                                    \
  { const float4* qp = (const float4*)(qbase + (size_t)(P) * (16 * D_)); \
    S0 = qp[0]; S1 = qp[1]; S2 = qp[2]; S3 = qp[3]; }

#define CVTW(S0, S1, S2, S3, BUF)                                   \
  { const unsigned w0 = cvt2fp8(S0.x, S0.y) | (cvt2fp8(S0.z, S0.w) << 16); \
    const unsigned w1 = cvt2fp8(S1.x, S1.y) | (cvt2fp8(S1.z, S1.w) << 16); \
    const unsigned w2 = cvt2fp8(S2.x, S2.y) | (cvt2fp8(S2.z, S2.w) << 16); \
    const unsigned w3 = cvt2fp8(S3.x, S3.y) | (cvt2fp8(S3.z, S3.w) << 16); \
    *(uint4*)(qs[BUF] + woff) = make_uint4(w0, w1, w2, w3); }

  // write-visibility barrier WITHOUT vmcnt drain (prefetch stays in flight)
#define PBAR()                                                      \
  { asm volatile("s_waitcnt lgkmcnt(0)" ::: "memory");              \
    __builtin_amdgcn_sched_barrier(0);                              \
    __builtin_amdgcn_s_barrier(); }

  // one 16-qrow phase: 8 ds_read_b64, 32 MFMA (4 slabs), 16 upd (+ rotating g)
#define CPHASE(BUF, ST)                                             \
  { const char* qb = qs[BUF] + l15 * D_ + h8;                       \
    f32x4 acc0 = fz, acc1 = fz, acc2 = fz, acc3 = fz;               \
    _Pragma("unroll")                                               \
    for (int kk = 0; kk < 8; ++kk) {                                \
      const long bf = *(const long*)(qb + ((((kk * 2 + l4h)) ^ l15) << 4)); \
      acc0 = __builtin_amdgcn_mfma_f32_16x16x32_fp8_fp8(afrag[0][kk], bf, acc0, 0, 0, 0); \
      acc1 = __builtin_amdgcn_mfma_f32_16x16x32_fp8_fp8(afrag[1][kk], bf, acc1, 0, 0, 0); \
      acc2 = __builtin_amdgcn_mfma_f32_16x16x32_fp8_fp8(afrag[2][kk], bf, acc2, 0, 0, 0); \
      acc3 = __builtin_amdgcn_mfma_f32_16x16x32_fp8_fp8(afrag[3][kk], bf, acc3, 0, 0, 0); \
    }                                                               \
    _Pragma("unroll")                                               \
    for (int r = 0; r < 4; ++r) {                                   \
      upd(mz[0][r], sz[0][r], acc0[r]); upd(mz[1][r], sz[1][r], acc1[r]); \
      upd(mz[2][r], sz[2][r], acc2[r]); upd(mz[3][r], sz[3][r], acc3[r]); \
    }                                                               \
    if (dog && (((ST) & 3) == wid)) {                               \
      f32x4 accg = fz;                                              \
      _Pragma("unroll")                                             \
      for (int kk = 0; kk < 8; ++kk) {                              \
        const long bf = *(const long*)(qb + ((((kk * 2 + l4h)) ^ l15) << 4)); \
        const long gb = *(const long*)(gBbase + kk * 32);           \
        accg = __builtin_amdgcn_mfma_f32_16x16x32_fp8_fp8(bf, gb, accg, 0, 0, 0); \
      }                                                             \
      _Pragma("unroll")                                             \
      for (int r = 0; r < 4; ++r) upd(mg, sg, accg[r]);             \
    } }

  // prologue: load P0,P1; stage P0; barrier (P1 loads remain in flight)
  LOADP(fa0, fa1, fa2, fa3, 0)
  LOADP(fb0, fb1, fb2, fb3, 1)
  CVTW(fa0, fa1, fa2, fa3, 0)
  PBAR()

  for (int i = 0; i < PH / 2; ++i) {
    const int t = 2 * i;
    // phase t (buf0): prefetch P(t+2); compute; stage P(t+1) -> buf1
    if (t + 2 < PH) LOADP(fa0, fa1, fa2, fa3, t + 2)
    CPHASE(0, t)
    CVTW(fb0, fb1, fb2, fb3, 1)
    PBAR()
    // phase t+1 (buf1): prefetch P(t+3); compute; stage P(t+2) -> buf0
    if (t + 3 < PH) LOADP(fb0, fb1, fb2, fb3, t + 3)
    CPHASE(1, t + 1)
    if (t + 2 < PH) CVTW(fa0, fa1, fa2, fa3, 0)
    PBAR()
  }

  // merge z-lse across the 16 column-lanes
#pragma unroll
  for (int s = 0; s < 4; ++s)
#pragma unroll
    for (int r = 0; r < 4; ++r) {
#pragma unroll
      for (int mask = 1; mask < 16; mask <<= 1) {
        const float om = __shfl_xor(mz[s][r], mask);
        const float os = __shfl_xor(sz[s][r], mask);
        merge_ms(mz[s][r], sz[s][r], om, os);
      }
    }
  if (l15 == 0) {
#pragma unroll
    for (int s = 0; s < 4; ++s)
#pragma unroll
      for (int r = 0; r < 4; ++r) {
        const int row = rg * 256 + wid * 64 + s * 16 + l4 * 4 + r;
        zpart[row * NCHUNK + chunk] = make_float2(mz[s][r], sz[s][r]);
      }
  }

  if (dog) {
    // merge g-lse across the 4 l4-groups
#pragma unroll
    for (int mask = 16; mask < 64; mask <<= 1) {
      const float om = __shfl_xor(mg, mask);
      const float os = __shfl_xor(sg, mask);
      merge_ms(mg, sg, om, os);
    }
    if (lane < 16) gbuf[wid][l15] = make_float2(mg, sg);
    __syncthreads();
    if (tid < 16) {
      float m = gbuf[0][tid].x, s = gbuf[0][tid].y;
      for (int w = 1; w < 4; ++w) merge_ms(m, s, gbuf[w][tid].x, gbuf[w][tid].y);
      gpart[tid * NCHUNK + chunk] = make_float2(m, s);
    }
  }
}

// ---------------- zmm: masked lse over the 512 z columns via bf16 MFMA ----------------
__global__ __launch_bounds__(512) void zmm_kernel(
    const short* __restrict__ Abf,
    float2* __restrict__ zcol, float* __restrict__ posll, float* __restrict__ posgl) {
  const int tid = threadIdx.x;
  const int wid = tid >> 6, lane = tid & 63;
  const int l15 = lane & 15, l4 = lane >> 4;
  const int r0 = blockIdx.x * 16;

  short8 af[8];
#pragma unroll
  for (int k = 0; k < 8; ++k)
    af[k] = *(const short8*)(Abf + (r0 + l15) * D_ + l4 * 8 + k * 32);

  float m[4], s[4];
#pragma unroll
  for (int r = 0; r < 4; ++r) { m[r] = -1e30f; s[r] = 0.f; }

  for (int st = 0; st < 4; ++st) {
    const int c0 = wid * 64 + st * 16;
    const f32x4 fz = {0.f, 0.f, 0.f, 0.f};
    f32x4 acc = fz;
#pragma unroll
    for (int k = 0; k < 8; ++k) {
      const short8 bq = *(const short8*)(Abf + (c0 + l15) * D_ + l4 * 8 + k * 32);
      acc = __builtin_amdgcn_mfma_f32_16x16x32_bf16(af[k], bq, acc, 0, 0, 0);
    }
#pragma unroll
    for (int r = 0; r < 4; ++r) {
      const int row = r0 + l4 * 4 + r;
      const int col = c0 + l15;
      const float v = acc[r] * INV_SCALE_A;  // log2-logit
      bool masked;
      if (r0 < NROWS_Z) {
        if (col == row + 1) posll[row] = v * LN2;
        masked = (col == row) || (col == row + 1);
      } else {
        const int b = row - NROWS_Z;
        const bool own = ((col >> 5) == b);
        if (own) posgl[col] = v * LN2;
        masked = own;
      }
      if (!masked) upd(m[r], s[r], v);
    }
  }
#pragma unroll
  for (int r = 0; r < 4; ++r) {
#pragma unroll
    for (int mask = 1; mask < 16; mask <<= 1) {
      const float om = __shfl_xor(m[r], mask);
      const float os = __shfl_xor(s[r], mask);
      merge_ms(m[r], s[r], om, os);
    }
  }
  __shared__ float2 lds[8][16];
  if (l15 == 0) {
#pragma unroll
    for (int r = 0; r < 4; ++r) lds[wid][l4 * 4 + r] = make_float2(m[r], s[r]);
  }
  __syncthreads();
  if (tid < 16) {
    float mm = lds[0][tid].x, ss = lds[0][tid].y;
    for (int w = 1; w < 8; ++w) merge_ms(mm, ss, lds[w][tid].x, lds[w][tid].y);
    zcol[r0 + tid] = make_float2(mm, ss);
  }
}

// ---------------- reduce: merge 256 chunk partials + zcol partial per row ----------------
__global__ void reduce_kernel(const float2* __restrict__ zpart, const float2* __restrict__ gpart,
                              const float2* __restrict__ zcol, float* __restrict__ lse_row) {
  const int r = blockIdx.x, tid = threadIdx.x;
  const float2 p = (r < NROWS_Z) ? zpart[r * NCHUNK + tid] : gpart[(r - NROWS_Z) * NCHUNK + tid];
  float m = p.x, s = p.y;
  __shared__ float2 red[4];
#pragma unroll
  for (int mask = 1; mask < 64; mask <<= 1) {
    const float om = __shfl_xor(m, mask);
    const float os = __shfl_xor(s, mask);
    merge_ms(m, s, om, os);
  }
  if ((tid & 63) == 0) red[tid >> 6] = make_float2(m, s);
  __syncthreads();
  if (tid == 0) {
    for (int w = 1; w < 4; ++w) merge_ms(m, s, red[w].x, red[w].y);
    const float2 zc = zcol[r];
    merge_ms(m, s, zc.x, zc.y);
    lse_row[r] = LN2 * (m + log2fast(s));   // back to natural log
  }
}

// ---------------- final: losses ----------------
__global__ void final_kernel(const float* __restrict__ lse_row, const float* __restrict__ posll,
                             const float* __restrict__ posgl, const float* __restrict__ smoothp,
                             float* __restrict__ out) {
  const int tid = threadIdx.x;
  float a_ll = 0.f, a_gl = 0.f, a_sm = 0.f;
  for (int i = tid; i < 496; i += 256) {
    const int b = i / 31, t = i - b * 31;
    const int a = b * 32 + t;
    const float pos = posll[a], lse = lse_row[a];
    const float d = lse - pos;
    a_ll += (d > 0.f) ? d + log1pf(__expf(-d)) : log1pf(__expf(d));
  }
  for (int i = tid; i < 512; i += 256) {
    const float pos = posgl[i], lse = lse_row[NROWS_Z + (i >> 5)];
    const float d = lse - pos;
    a_gl += (d > 0.f) ? d + log1pf(__expf(-d)) : log1pf(__expf(d));
  }
  for (int i = tid; i < 512; i += 256) a_sm += smoothp[i];

  __shared__ float red[4];
  float sums[3] = {a_ll, a_gl, a_sm};
  float tot[3];
  for (int j = 0; j < 3; ++j) {
    float v = sums[j];
#pragma unroll
    for (int mask = 1; mask < 64; mask <<= 1) v += __shfl_xor(v, mask);
    __syncthreads();
    if ((tid & 63) == 0) red[tid >> 6] = v;
    __syncthreads();
    tot[j] = red[0] + red[1] + red[2] + red[3];
  }
  if (tid == 0)
    out[0] = tot[0] / 496.f + 0.5f * (tot[1] / 512.f) + 0.1f * (tot[2] / 496.f);
}

extern "C" void kernel_launch(void* const* d_in, const int* in_sizes, int n_in,
                              void* d_out, int out_size, void* d_ws, size_t ws_size,
                              hipStream_t stream) {
  const float* z = (const float*)d_in[0];      // [512,256]
  const float* g = (const float*)d_in[1];      // [16,256]
  const float* queue = (const float*)d_in[3];  // [131072,256]
  float* out = (float*)d_out;
  char* ws = (char*)d_ws;

  const size_t offA = 0;                        // 528*256*2 = 270336
  const size_t offA8 = 270336;                  // 528*256   = 135168
  const size_t offZpart = offA8 + 135168;       // 512*256*8 = 1048576
  const size_t offGpart = offZpart + 1048576;   // 16*256*8  = 32768
  const size_t offZcol = offGpart + 32768;      // 528*8     = 4224
  const size_t offPosll = offZcol + 4224;
  const size_t offPosgl = offPosll + 2048;
  const size_t offSm = offPosgl + 2048;
  const size_t offLse = offSm + 2048;

  short* Abf = (short*)(ws + offA);
  char* Abf8 = (char*)(ws + offA8);
  float2* zpart = (float2*)(ws + offZpart);
  float2* gpart = (float2*)(ws + offGpart);
  float2* zcol = (float2*)(ws + offZcol);
  float* posll = (float*)(ws + offPosll);
  float* posgl = (float*)(ws + offPosgl);
  float* smoothp = (float*)(ws + offSm);
  float* lse_row = (float*)(ws + offLse);

  prep_kernel<<<NROWS, 256, 0, stream>>>(z, g, Abf, Abf8, smoothp);
  big_kernel<<<512, 256, 0, stream>>>(queue, Abf8, zpart, gpart);
  zmm_kernel<<<33, 512, 0, stream>>>(Abf, zcol, posll, posgl);
  reduce_kernel<<<NROWS, NCHUNK, 0, stream>>>(zpart, gpart, zcol, lse_row);
  final_kernel<<<1, 256, 0, stream>>>(lse_row, posll, posgl, smoothp, out);
}